// Round 8
// baseline (318.482 us; speedup 1.0000x reference)
//
#include <hip/hip_runtime.h>
#include <stdint.h>

#define ROWS 1024
#define IDIM 256
#define HDIM 1024

// ---------------- threefry2x32 (key = [0,42]) ----------------
__device__ __forceinline__ uint32_t rotl32(uint32_t x, int r){ return (x<<r)|(x>>(32-r)); }

__device__ __forceinline__ void threefry(uint32_t x0, uint32_t x1, uint32_t& o0, uint32_t& o1){
  const uint32_t k0 = 0u, k1 = 42u;
  const uint32_t k2 = 0x1BD11BDAu ^ k0 ^ k1;
  x0 += k0; x1 += k1;
#define TFR(r) { x0 += x1; x1 = rotl32(x1, r); x1 ^= x0; }
  TFR(13) TFR(15) TFR(26) TFR(6)  x0 += k1; x1 += k2 + 1u;
  TFR(17) TFR(29) TFR(16) TFR(24) x0 += k2; x1 += k0 + 2u;
  TFR(13) TFR(15) TFR(26) TFR(6)  x0 += k0; x1 += k1 + 3u;
  TFR(17) TFR(29) TFR(16) TFR(24) x0 += k1; x1 += k2 + 4u;
  TFR(13) TFR(15) TFR(26) TFR(6)  x0 += k2; x1 += k0 + 5u;
#undef TFR
  o0 = x0; o1 = x1;
}

// JAX >=0.4.36 partitionable threefry: counter=(0,i), draw = o0^o1  [verified R7]
__global__ __launch_bounds__(256) void mask_kernel(const float* __restrict__ freq,
                                                   float* __restrict__ mkf)
{
  uint32_t i = blockIdx.x * 256u + threadIdx.x;   // [0, 2^20)
  uint32_t o0, o1;
  threefry(0u, i, o0, o1);
  uint32_t bits = o0 ^ o1;
  float u = __uint_as_float((bits >> 9) | 0x3F800000u) - 1.0f;
  mkf[i] = (u < freq[i & 1023u]) ? 1.0f : 0.0f;
}

// ---------------- argaug: fp32 bulk + fp64-exact rescue ----------------
// Decision function identical to the R7-passing all-fp64 kernel: every candidate
// within eps=1e-3 of the fp32 max (global and theta0) is recomputed in fp64 with
// the same ascending-q summation order; winner picked with lex-first (t,s).
__global__ __launch_bounds__(256) void argaug_kernel(const float* __restrict__ x,
                                                     const float* __restrict__ y,
                                                     float* __restrict__ xaug)
{
  __shared__ float  xs[IDIM];
  __shared__ float  ys[IDIM];
  __shared__ float  kp[1024];
  __shared__ double P[1025];       // fp64 prefix of kp^2
  __shared__ float  vst[5888];     // 9*640 sims (padded to 23*256)
  __shared__ double rv[256];
  __shared__ int    rk[256];
  __shared__ double wv[4];
  __shared__ int    cnt;
  __shared__ int    list[128];

  const int tid  = threadIdx.x;
  const int wave = tid >> 6;
  const int lane = tid & 63;
  const int row  = blockIdx.x;

  xs[tid] = x[row * IDIM + tid];
  ys[tid] = y[row * IDIM + tid];
#pragma unroll
  for (int i = tid; i < 5888; i += 256) vst[i] = -1.0e30f;
  const int sbase = 192 * wave + 3 * lane;

  for (int t = 0; t < 9; ++t) {
    const int OL = 128 + 32 * t;
    const double ratio = 256.0 / (double)OL;

    __syncthreads();   // prior-iter readers done (also covers initial xs/ys)
    for (int i = tid; i < 1024; i += 256) {
      float v = 0.0f;
      int j = i - 255;
      if (j >= 0 && j < OL) v = xs[(int)floor((double)j * ratio)];  // fp64 = numpy
      kp[i] = v;
    }
    __syncthreads();

    // fp64 prefix of kp^2 (shuffle scan; order-insensitive, bulk-only)
    {
      double d0 = (double)kp[4*tid+0]; d0 *= d0;
      double d1 = (double)kp[4*tid+1]; d1 *= d1;
      double d2 = (double)kp[4*tid+2]; d2 *= d2;
      double d3 = (double)kp[4*tid+3]; d3 *= d3;
      double p1 = d0, p2 = p1 + d1, p3 = p2 + d2, p4 = p3 + d3;
      double sc = p4;
#pragma unroll
      for (int d = 1; d < 64; d <<= 1) {
        double u = __shfl_up(sc, d, 64);
        if (lane >= d) sc += u;
      }
      if (lane == 63) wv[wave] = sc;
      __syncthreads();
      double wo = 0.0;
      if (wave > 0) wo += wv[0];
      if (wave > 1) wo += wv[1];
      if (wave > 2) wo += wv[2];
      double excl = wo + (sc - p4);
      P[4*tid+1] = excl + p1; P[4*tid+2] = excl + p2;
      P[4*tid+3] = excl + p3; P[4*tid+4] = excl + p4;
      if (tid == 0) P[0] = 0.0;
      __syncthreads();
    }

    // fp32 dot pass (3 shifts/lane, register-rotated kp window)
    float a0 = 0.f, a1 = 0.f, a2 = 0.f;
    const int qlo = (wave == 0) ? 64 : 0;             // skips exact zeros only
    const int qhi = min(256, 255 + OL - 192 * wave);
    if (qhi > qlo) {
      int p = sbase + qlo;
      float c0 = kp[p], c1 = kp[p+1], c2 = kp[p+2], c3;
      for (int q = qlo; q < qhi; q += 4) {
        float4 y4 = *(const float4*)&ys[q];
        a0 += y4.x*c0; a1 += y4.x*c1; a2 += y4.x*c2;
        c3 = kp[p+3];
        a0 += y4.y*c1; a1 += y4.y*c2; a2 += y4.y*c3;
        c0 = kp[p+4];
        a0 += y4.z*c2; a1 += y4.z*c3; a2 += y4.z*c0;
        c1 = kp[p+5];
        a0 += y4.w*c3; a1 += y4.w*c0; a2 += y4.w*c1;
        c2 = kp[p+6];
        p += 4;
      }
    }
    const int nsh = OL + 255;
#pragma unroll
    for (int r = 0; r < 3; ++r) {
      int s = sbase + r;
      if (s < nsh) {
        float a = (r == 0) ? a0 : (r == 1) ? a1 : a2;
        float nf = (float)(P[s+256] - P[s]);
        if (nf > 0.f) vst[t*640 + s] = a / sqrtf(nf);
      }
    }
  }
  __syncthreads();

  // fp32 maxima (global + theta0)
  {
    float gm = -1.0e30f;
    for (int i = tid; i < 5888; i += 256) gm = fmaxf(gm, vst[i]);
    rv[tid] = (double)gm;
    __syncthreads();
    for (int off = 128; off > 0; off >>= 1) {
      if (tid < off) rv[tid] = fmax(rv[tid], rv[tid+off]);
      __syncthreads();
    }
  }
  const float gmax32 = (float)rv[0];
  __syncthreads();
  {
    float tm = -1.0e30f;
    for (int i = tid; i < 640; i += 256) tm = fmaxf(tm, vst[i]);
    rv[tid] = (double)tm;
    __syncthreads();
    for (int off = 128; off > 0; off >>= 1) {
      if (tid < off) rv[tid] = fmax(rv[tid], rv[tid+off]);
      __syncthreads();
    }
  }
  const float t0max32 = (float)rv[0];

  // collect rescue set (|v32 - v64| < 3e-4 bound -> eps 1e-3 always contains winners)
  if (tid == 0) cnt = 0;
  __syncthreads();
  const float gthr = gmax32 - 1.0e-3f;
  const float tthr = t0max32 - 1.0e-3f;
  for (int i = tid; i < 5888; i += 256) {
    float v = vst[i];
    if (v >= gthr || (i < 640 && v >= tthr)) {
      int id = atomicAdd(&cnt, 1);
      if (id < 128) list[id] = i;
    }
  }
  __syncthreads();
  const int m = min(cnt, 128);

  // fp64 exact recompute (bit-identical to R7 kernel: ascending q, pads are +0.0)
  double v64 = -1.0e300; int key = 0x3FFFFFFF;
  if (tid < m) {
    int slot = list[tid];
    int tt = slot / 640;
    int ss = slot - tt * 640;
    int OLr = 128 + 32 * tt;
    double ratior = 256.0 / (double)OLr;
    double a64 = 0.0, n64 = 0.0;
    for (int q = 0; q < 256; ++q) {
      int j = ss + q - 255;
      double c = 0.0;
      if (j >= 0 && j < OLr) c = (double)xs[(int)floor((double)j * ratior)];
      a64 += (double)ys[q] * c;
      n64 += c * c;
    }
    if (n64 > 0.0) { v64 = a64 / sqrt(n64); key = (tt << 10) | ss; }
  }

  // reduce #1: global best, lex-first (t,s)
  rv[tid] = v64; rk[tid] = key;
  __syncthreads();
  for (int off = 128; off > 0; off >>= 1) {
    if (tid < off) {
      double v2 = rv[tid+off]; int k2 = rk[tid+off];
      if (v2 > rv[tid] || (v2 == rv[tid] && k2 < rk[tid])) { rv[tid] = v2; rk[tid] = k2; }
    }
    __syncthreads();
  }
  const double gbest = rv[0];
  const int    gk    = rk[0];
  __syncthreads();

  // reduce #2: theta0 best (fallback when gbest <= 0)
  rv[tid] = ((key >> 10) == 0) ? v64 : -1.0e300;
  rk[tid] = key;
  __syncthreads();
  for (int off = 128; off > 0; off >>= 1) {
    if (tid < off) {
      double v2 = rv[tid+off]; int k2 = rk[tid+off];
      if (v2 > rv[tid] || (v2 == rv[tid] && k2 < rk[tid])) { rv[tid] = v2; rk[tid] = k2; }
    }
    __syncthreads();
  }
  const int wk = (gbest > 0.0) ? gk : rk[0];

  const int tb = wk >> 10, sb = wk & 1023;
  const int OLb = 128 + 32 * tb;
  const double ratiob = 256.0 / (double)OLb;
  int j = sb + tid - 255;
  float v = 0.0f;
  if (j >= 0 && j < OLb) v = xs[(int)floor((double)j * ratiob)];
  xaug[row * IDIM + tid] = v;
}

// ---------------- GEMM1: h = (xaug @ W1 + b1) * mk  (1024x256 @ 256x1024) ----------------
__global__ __launch_bounds__(256) void gemm1_kernel(const float* __restrict__ A,
                                                    const float* __restrict__ W1,
                                                    const float* __restrict__ b1,
                                                    const float* __restrict__ mkf,
                                                    float* __restrict__ h)
{
  __shared__ float As[32][68];
  __shared__ float Bs[32][68];
  const int tid = threadIdx.x;
  const int m0 = blockIdx.x * 64;
  const int n0 = blockIdx.y * 64;
  const int tx = tid & 15, ty = tid >> 4;
  float acc[4][4] = {};

  for (int kt = 0; kt < 256; kt += 32) {
#pragma unroll
    for (int jj = 0; jj < 8; ++jj) {
      int f = tid + 256*jj;
      As[f & 31][f >> 5] = A[(m0 + (f >> 5)) * 256 + kt + (f & 31)];
    }
#pragma unroll
    for (int jj = 0; jj < 8; ++jj) {
      int f = tid + 256*jj;
      Bs[f >> 6][f & 63] = W1[(kt + (f >> 6)) * 1024 + n0 + (f & 63)];
    }
    __syncthreads();
#pragma unroll
    for (int kk = 0; kk < 32; ++kk) {
      float4 a4 = *(const float4*)&As[kk][4*ty];
      float4 b4 = *(const float4*)&Bs[kk][4*tx];
      acc[0][0] += a4.x*b4.x; acc[0][1] += a4.x*b4.y; acc[0][2] += a4.x*b4.z; acc[0][3] += a4.x*b4.w;
      acc[1][0] += a4.y*b4.x; acc[1][1] += a4.y*b4.y; acc[1][2] += a4.y*b4.z; acc[1][3] += a4.y*b4.w;
      acc[2][0] += a4.z*b4.x; acc[2][1] += a4.z*b4.y; acc[2][2] += a4.z*b4.z; acc[2][3] += a4.z*b4.w;
      acc[3][0] += a4.w*b4.x; acc[3][1] += a4.w*b4.y; acc[3][2] += a4.w*b4.z; acc[3][3] += a4.w*b4.w;
    }
    __syncthreads();
  }

  float4 bias = *(const float4*)&b1[n0 + 4*tx];
#pragma unroll
  for (int r = 0; r < 4; ++r) {
    int mm = m0 + 4*ty + r;
    float4 mk4 = *(const float4*)&mkf[mm * 1024 + n0 + 4*tx];
    float4 o;
    o.x = (acc[r][0] + bias.x) * mk4.x;
    o.y = (acc[r][1] + bias.y) * mk4.y;
    o.z = (acc[r][2] + bias.z) * mk4.z;
    o.w = (acc[r][3] + bias.w) * mk4.w;
    *(float4*)&h[mm * 1024 + n0 + 4*tx] = o;
  }
}

// ---------------- GEMM2 (split-K=4): out_acc += h @ W2  (1024x1024 @ 1024x256) ----------------
__global__ __launch_bounds__(256) void gemm2_kernel(const float* __restrict__ h,
                                                    const float* __restrict__ W2,
                                                    float* __restrict__ out_acc)
{
  __shared__ float As[32][68];
  __shared__ float Bs[32][68];
  const int tid = threadIdx.x;
  const int m0 = blockIdx.x * 64;
  const int n0 = blockIdx.y * 64;
  const int kz = blockIdx.z * 256;
  const int tx = tid & 15, ty = tid >> 4;
  float acc[4][4] = {};

  for (int kt = 0; kt < 256; kt += 32) {
#pragma unroll
    for (int jj = 0; jj < 8; ++jj) {
      int f = tid + 256*jj;
      As[f & 31][f >> 5] = h[(m0 + (f >> 5)) * 1024 + kz + kt + (f & 31)];
    }
#pragma unroll
    for (int jj = 0; jj < 8; ++jj) {
      int f = tid + 256*jj;
      Bs[f >> 6][f & 63] = W2[(kz + kt + (f >> 6)) * 256 + n0 + (f & 63)];
    }
    __syncthreads();
#pragma unroll
    for (int kk = 0; kk < 32; ++kk) {
      float4 a4 = *(const float4*)&As[kk][4*ty];
      float4 b4 = *(const float4*)&Bs[kk][4*tx];
      acc[0][0] += a4.x*b4.x; acc[0][1] += a4.x*b4.y; acc[0][2] += a4.x*b4.z; acc[0][3] += a4.x*b4.w;
      acc[1][0] += a4.y*b4.x; acc[1][1] += a4.y*b4.y; acc[1][2] += a4.y*b4.z; acc[1][3] += a4.y*b4.w;
      acc[2][0] += a4.z*b4.x; acc[2][1] += a4.z*b4.y; acc[2][2] += a4.z*b4.z; acc[2][3] += a4.z*b4.w;
      acc[3][0] += a4.w*b4.x; acc[3][1] += a4.w*b4.y; acc[3][2] += a4.w*b4.z; acc[3][3] += a4.w*b4.w;
    }
    __syncthreads();
  }

#pragma unroll
  for (int r = 0; r < 4; ++r)
#pragma unroll
    for (int c = 0; c < 4; ++c)
      unsafeAtomicAdd(&out_acc[(m0 + 4*ty + r) * 256 + n0 + 4*tx + c], acc[r][c]);
}

// ---------------- finalize: out = acc + b2 + xaug; loss partials ----------------
__global__ __launch_bounds__(256) void finalize_kernel(const float* __restrict__ out_acc,
                                                       const float* __restrict__ b2,
                                                       const float* __restrict__ xaug,
                                                       const float* __restrict__ yref,
                                                       float* __restrict__ d_out,
                                                       double* __restrict__ loss_acc,
                                                       unsigned int* __restrict__ cnt_acc)
{
  __shared__ double sred[4];
  __shared__ unsigned int cred[4];
  int i = blockIdx.x * 256 + threadIdx.x;
  int n = i & 255;
  float v = out_acc[i] + b2[n] + xaug[i];
  d_out[1 + i] = v;
  float yv = yref[i];
  bool valid = (yv != 0.0f);
  float df = v - yv;
  double lsd = valid ? (double)df * (double)df : 0.0;
#pragma unroll
  for (int off = 32; off > 0; off >>= 1) lsd += __shfl_down(lsd, off, 64);
  unsigned long long bal = __ballot(valid);
  int wvx = threadIdx.x >> 6, ln = threadIdx.x & 63;
  if (ln == 0) { sred[wvx] = lsd; cred[wvx] = (unsigned int)__popcll(bal); }
  __syncthreads();
  if (threadIdx.x == 0) {
    double s = sred[0] + sred[1] + sred[2] + sred[3];
    unsigned int c = cred[0] + cred[1] + cred[2] + cred[3];
    atomicAdd(loss_acc, s);
    atomicAdd(cnt_acc, c);
  }
}

__global__ void loss_kernel(const double* __restrict__ loss_acc,
                            const unsigned int* __restrict__ cnt_acc,
                            float* __restrict__ d_out)
{
  d_out[0] = (float)(loss_acc[0] / (double)cnt_acc[0]);
}

// ---------------- launch ----------------
extern "C" void kernel_launch(void* const* d_in, const int* in_sizes, int n_in,
                              void* d_out, int out_size, void* d_ws, size_t ws_size,
                              hipStream_t stream) {
  const float* x    = (const float*)d_in[0];
  const float* y    = (const float*)d_in[1];
  const float* W1   = (const float*)d_in[2];
  const float* b1   = (const float*)d_in[3];
  const float* W2   = (const float*)d_in[4];
  const float* b2   = (const float*)d_in[5];
  const float* freq = (const float*)d_in[6];
  float* out = (float*)d_out;

  char* ws = (char*)d_ws;
  float*  xaug = (float*)(ws);                        // 1 MB
  float*  h    = (float*)(ws + (1u<<20));             // 4 MB
  float*  mkf  = (float*)(ws + 5u*(1u<<20));          // 4 MB
  float*  oacc = (float*)(ws + 9u*(1u<<20));          // 1 MB
  double* lacc = (double*)(ws + 10u*(1u<<20));        // 8 B
  unsigned int* cacc = (unsigned int*)(ws + 10u*(1u<<20) + 8u);

  hipMemsetAsync(ws + 9u*(1u<<20), 0, (1u<<20) + 16u, stream);

  mask_kernel  <<<4096, 256, 0, stream>>>(freq, mkf);
  argaug_kernel<<<1024, 256, 0, stream>>>(x, y, xaug);
  gemm1_kernel <<<dim3(16,16),  256, 0, stream>>>(xaug, W1, b1, mkf, h);
  gemm2_kernel <<<dim3(16,4,4), 256, 0, stream>>>(h, W2, oacc);
  finalize_kernel<<<1024, 256, 0, stream>>>(oacc, b2, xaug, y, out, lacc, cacc);
  loss_kernel  <<<1, 1, 0, stream>>>(lacc, cacc, out);
}

// Round 10
// 250.490 us; speedup vs baseline: 1.2714x; 1.2714x over previous
//
#include <hip/hip_runtime.h>
#include <stdint.h>

#define ROWS 1024
#define IDIM 256
#define HDIM 1024

// ---------------- threefry2x32 (key = [0,42]) ----------------
__device__ __forceinline__ uint32_t rotl32(uint32_t x, int r){ return (x<<r)|(x>>(32-r)); }

__device__ __forceinline__ void threefry(uint32_t x0, uint32_t x1, uint32_t& o0, uint32_t& o1){
  const uint32_t k0 = 0u, k1 = 42u;
  const uint32_t k2 = 0x1BD11BDAu ^ k0 ^ k1;
  x0 += k0; x1 += k1;
#define TFR(r) { x0 += x1; x1 = rotl32(x1, r); x1 ^= x0; }
  TFR(13) TFR(15) TFR(26) TFR(6)  x0 += k1; x1 += k2 + 1u;
  TFR(17) TFR(29) TFR(16) TFR(24) x0 += k2; x1 += k0 + 2u;
  TFR(13) TFR(15) TFR(26) TFR(6)  x0 += k0; x1 += k1 + 3u;
  TFR(17) TFR(29) TFR(16) TFR(24) x0 += k1; x1 += k2 + 4u;
  TFR(13) TFR(15) TFR(26) TFR(6)  x0 += k2; x1 += k0 + 5u;
#undef TFR
  o0 = x0; o1 = x1;
}

// JAX >=0.4.36 partitionable threefry: counter=(0,i), draw = o0^o1  [verified R7]
__global__ __launch_bounds__(256) void mask_kernel(const float* __restrict__ freq,
                                                   float* __restrict__ mkf)
{
  uint32_t i = blockIdx.x * 256u + threadIdx.x;   // [0, 2^20)
  uint32_t o0, o1;
  threefry(0u, i, o0, o1);
  uint32_t bits = o0 ^ o1;
  float u = __uint_as_float((bits >> 9) | 0x3F800000u) - 1.0f;
  mkf[i] = (u < freq[i & 1023u]) ? 1.0f : 0.0f;
}

// ---------------- argaug: fp32 bulk (regs) + wave-parallel fp64 rescue ----------------
// R8 lesson: keep R7's 2-barrier loop structure; LDS <= ~11KB so the grid's
// natural 4 blocks/CU stay co-resident. Bulk sims live in REGISTERS (t-loop
// fully unrolled -> static indexing, rule #20). Rescue: every candidate within
// eps=1e-3 of the fp32 max (bound |sim32-sim64| ~ 6e-5) is recomputed exactly
// in fp64 (one wave per candidate, butterfly reduce -> deterministic; identical
// window content => bitwise-identical value => lex-min (t,s) tie-break
// reproduces the reference's first-occurrence semantics).
__global__ __launch_bounds__(256) void argaug_kernel(const float* __restrict__ x,
                                                     const float* __restrict__ y,
                                                     float* __restrict__ xaug)
{
  __shared__ float  xs[IDIM];
  __shared__ float  ys[IDIM];
  __shared__ float  kp[1024];
  __shared__ double rv[256];
  __shared__ int    rk[256];
  __shared__ double cand_v[128];
  __shared__ int    cand_k[128];
  __shared__ int    list[128];
  __shared__ int    cnt;

  const int tid  = threadIdx.x;
  const int wave = tid >> 6;
  const int lane = tid & 63;
  const int row  = blockIdx.x;

  xs[tid] = x[row * IDIM + tid];
  ys[tid] = y[row * IDIM + tid];
  if (tid == 0) cnt = 0;
  const int sbase = 192 * wave + 3 * lane;

  float s0[9], s1[9], s2[9];   // statically indexed via full unroll

#pragma unroll
  for (int t = 0; t < 9; ++t) {
    const int OL = 128 + 32 * t;
    const double ratio = 256.0 / (double)OL;

    __syncthreads();           // covers initial xs/ys load and prior-iter kp readers
#pragma unroll
    for (int ii = 0; ii < 4; ++ii) {
      int i = tid + 256 * ii;
      float v = 0.0f;
      int j = i - 255;
      if (j >= 0 && j < OL) v = xs[(int)floor((double)j * ratio)];  // fp64 = numpy
      kp[i] = v;
    }
    __syncthreads();

    float a0=0.f,a1=0.f,a2=0.f, n0=0.f,n1=0.f,n2=0.f;
    const int qlo = (wave == 0) ? 64 : 0;              // skipped terms are exact zeros
    const int qhi = min(256, 255 + OL - 192 * wave);
    if (qhi > qlo) {
      int p = sbase + qlo;
      float c0 = kp[p], c1 = kp[p+1], c2 = kp[p+2], c3;
      for (int q = qlo; q < qhi; q += 4) {
        float4 y4 = *(const float4*)&ys[q];
        a0 += y4.x*c0; n0 += c0*c0;
        a1 += y4.x*c1; n1 += c1*c1;
        a2 += y4.x*c2; n2 += c2*c2;
        c3 = kp[p+3];
        a0 += y4.y*c1; a1 += y4.y*c2; a2 += y4.y*c3; n0 += c1*c1; n1 += c2*c2; n2 += c3*c3;
        c0 = kp[p+4];
        a0 += y4.z*c2; a1 += y4.z*c3; a2 += y4.z*c0; n0 += c2*c2; n1 += c3*c3; n2 += c0*c0;
        c1 = kp[p+5];
        a0 += y4.w*c3; a1 += y4.w*c0; a2 += y4.w*c1; n0 += c3*c3; n1 += c0*c0; n2 += c1*c1;
        c2 = kp[p+6];
        p += 4;
      }
    }
    const int nsh = OL + 255;
    s0[t] = (sbase     < nsh && n0 > 0.f) ? a0 * __frsqrt_rn(n0) : -1.0e30f;
    s1[t] = (sbase + 1 < nsh && n1 > 0.f) ? a1 * __frsqrt_rn(n1) : -1.0e30f;
    s2[t] = (sbase + 2 < nsh && n2 > 0.f) ? a2 * __frsqrt_rn(n2) : -1.0e30f;
  }
  __syncthreads();

  // fp32 maxima: global and theta0
  {
    float gm = -1.0e30f;
#pragma unroll
    for (int t = 0; t < 9; ++t) gm = fmaxf(gm, fmaxf(s0[t], fmaxf(s1[t], s2[t])));
    rv[tid] = (double)gm;
  }
  __syncthreads();
  for (int off = 128; off > 0; off >>= 1) {
    if (tid < off) rv[tid] = fmax(rv[tid], rv[tid+off]);
    __syncthreads();
  }
  const float gmax32 = (float)rv[0];
  __syncthreads();
  rv[tid] = (double)fmaxf(s0[0], fmaxf(s1[0], s2[0]));
  __syncthreads();
  for (int off = 128; off > 0; off >>= 1) {
    if (tid < off) rv[tid] = fmax(rv[tid], rv[tid+off]);
    __syncthreads();
  }
  const float t0max32 = (float)rv[0];

  // collect rescue candidates (eps = 1e-3 >> 6e-5 error bound)
  const float gthr = gmax32  - 1.0e-3f;
  const float tthr = t0max32 - 1.0e-3f;
#pragma unroll
  for (int t = 0; t < 9; ++t) {
#pragma unroll
    for (int r = 0; r < 3; ++r) {
      float v = (r == 0) ? s0[t] : (r == 1) ? s1[t] : s2[t];
      if (v >= gthr || (t == 0 && v >= tthr)) {
        int id = atomicAdd(&cnt, 1);
        if (id < 128) list[id] = (t << 10) | (sbase + r);
      }
    }
  }
  __syncthreads();
  const int m = min(cnt, 128);

  // fp64 exact recompute: one wave per candidate, butterfly reduce (deterministic)
  for (int c = wave; c < m; c += 4) {
    const int slot = list[c];
    const int tt = slot >> 10, ss = slot & 1023;
    const int OLr = 128 + 32 * tt;
    const double ratior = 256.0 / (double)OLr;
    double a64 = 0.0, n64 = 0.0;
#pragma unroll
    for (int k = 0; k < 4; ++k) {
      int q = 4 * lane + k;
      int j = ss + q - 255;
      if (j >= 0 && j < OLr) {
        double cc = (double)xs[(int)floor((double)j * ratior)];
        a64 += (double)ys[q] * cc;
        n64 += cc * cc;
      }
    }
#pragma unroll
    for (int d = 1; d < 64; d <<= 1) {
      a64 += __shfl_xor(a64, d, 64);
      n64 += __shfl_xor(n64, d, 64);
    }
    if (lane == 0) {
      cand_v[c] = (n64 > 0.0) ? a64 / sqrt(n64) : -1.0e300;
      cand_k[c] = slot;
    }
  }
  __syncthreads();

  // reduce #1: global best among rescued, lex-first (t,s)
  rv[tid] = (tid < m) ? cand_v[tid] : -1.0e300;
  rk[tid] = (tid < m) ? cand_k[tid] : 0x3FFFFFFF;
  __syncthreads();
  for (int off = 128; off > 0; off >>= 1) {
    if (tid < off) {
      double v2 = rv[tid+off]; int k2 = rk[tid+off];
      if (v2 > rv[tid] || (v2 == rv[tid] && k2 < rk[tid])) { rv[tid] = v2; rk[tid] = k2; }
    }
    __syncthreads();
  }
  const double gbest = rv[0];
  const int    gk    = rk[0];
  __syncthreads();

  // reduce #2: theta0 best (fallback when gbest <= 0)
  rv[tid] = (tid < m && (cand_k[tid] >> 10) == 0) ? cand_v[tid] : -1.0e300;
  rk[tid] = (tid < m) ? cand_k[tid] : 0x3FFFFFFF;
  __syncthreads();
  for (int off = 128; off > 0; off >>= 1) {
    if (tid < off) {
      double v2 = rv[tid+off]; int k2 = rk[tid+off];
      if (v2 > rv[tid] || (v2 == rv[tid] && k2 < rk[tid])) { rv[tid] = v2; rk[tid] = k2; }
    }
    __syncthreads();
  }
  const int wk = (gbest > 0.0) ? gk : rk[0];

  const int tb = wk >> 10, sb = wk & 1023;
  const int OLb = 128 + 32 * tb;
  const double ratiob = 256.0 / (double)OLb;
  int j = sb + tid - 255;
  float v = 0.0f;
  if (j >= 0 && j < OLb) v = xs[(int)floor((double)j * ratiob)];
  xaug[row * IDIM + tid] = v;
}

// ---------------- GEMM1: h = (xaug @ W1 + b1) * mk  (1024x256 @ 256x1024) ----------------
__global__ __launch_bounds__(256) void gemm1_kernel(const float* __restrict__ A,
                                                    const float* __restrict__ W1,
                                                    const float* __restrict__ b1,
                                                    const float* __restrict__ mkf,
                                                    float* __restrict__ h)
{
  __shared__ float As[32][68];
  __shared__ float Bs[32][68];
  const int tid = threadIdx.x;
  const int m0 = blockIdx.x * 64;
  const int n0 = blockIdx.y * 64;
  const int tx = tid & 15, ty = tid >> 4;
  float acc[4][4] = {};

  for (int kt = 0; kt < 256; kt += 32) {
#pragma unroll
    for (int jj = 0; jj < 8; ++jj) {
      int f = tid + 256*jj;
      As[f & 31][f >> 5] = A[(m0 + (f >> 5)) * 256 + kt + (f & 31)];
    }
#pragma unroll
    for (int jj = 0; jj < 8; ++jj) {
      int f = tid + 256*jj;
      Bs[f >> 6][f & 63] = W1[(kt + (f >> 6)) * 1024 + n0 + (f & 63)];
    }
    __syncthreads();
#pragma unroll
    for (int kk = 0; kk < 32; ++kk) {
      float4 a4 = *(const float4*)&As[kk][4*ty];
      float4 b4 = *(const float4*)&Bs[kk][4*tx];
      acc[0][0] += a4.x*b4.x; acc[0][1] += a4.x*b4.y; acc[0][2] += a4.x*b4.z; acc[0][3] += a4.x*b4.w;
      acc[1][0] += a4.y*b4.x; acc[1][1] += a4.y*b4.y; acc[1][2] += a4.y*b4.z; acc[1][3] += a4.y*b4.w;
      acc[2][0] += a4.z*b4.x; acc[2][1] += a4.z*b4.y; acc[2][2] += a4.z*b4.z; acc[2][3] += a4.z*b4.w;
      acc[3][0] += a4.w*b4.x; acc[3][1] += a4.w*b4.y; acc[3][2] += a4.w*b4.z; acc[3][3] += a4.w*b4.w;
    }
    __syncthreads();
  }

  float4 bias = *(const float4*)&b1[n0 + 4*tx];
#pragma unroll
  for (int r = 0; r < 4; ++r) {
    int mm = m0 + 4*ty + r;
    float4 mk4 = *(const float4*)&mkf[mm * 1024 + n0 + 4*tx];
    float4 o;
    o.x = (acc[r][0] + bias.x) * mk4.x;
    o.y = (acc[r][1] + bias.y) * mk4.y;
    o.z = (acc[r][2] + bias.z) * mk4.z;
    o.w = (acc[r][3] + bias.w) * mk4.w;
    *(float4*)&h[mm * 1024 + n0 + 4*tx] = o;
  }
}

// ---------------- GEMM2 (split-K=4): out_acc += h @ W2  (1024x1024 @ 1024x256) ----------------
__global__ __launch_bounds__(256) void gemm2_kernel(const float* __restrict__ h,
                                                    const float* __restrict__ W2,
                                                    float* __restrict__ out_acc)
{
  __shared__ float As[32][68];
  __shared__ float Bs[32][68];
  const int tid = threadIdx.x;
  const int m0 = blockIdx.x * 64;
  const int n0 = blockIdx.y * 64;
  const int kz = blockIdx.z * 256;
  const int tx = tid & 15, ty = tid >> 4;
  float acc[4][4] = {};

  for (int kt = 0; kt < 256; kt += 32) {
#pragma unroll
    for (int jj = 0; jj < 8; ++jj) {
      int f = tid + 256*jj;
      As[f & 31][f >> 5] = h[(m0 + (f >> 5)) * 1024 + kz + kt + (f & 31)];
    }
#pragma unroll
    for (int jj = 0; jj < 8; ++jj) {
      int f = tid + 256*jj;
      Bs[f >> 6][f & 63] = W2[(kz + kt + (f >> 6)) * 256 + n0 + (f & 63)];
    }
    __syncthreads();
#pragma unroll
    for (int kk = 0; kk < 32; ++kk) {
      float4 a4 = *(const float4*)&As[kk][4*ty];
      float4 b4 = *(const float4*)&Bs[kk][4*tx];
      acc[0][0] += a4.x*b4.x; acc[0][1] += a4.x*b4.y; acc[0][2] += a4.x*b4.z; acc[0][3] += a4.x*b4.w;
      acc[1][0] += a4.y*b4.x; acc[1][1] += a4.y*b4.y; acc[1][2] += a4.y*b4.z; acc[1][3] += a4.y*b4.w;
      acc[2][0] += a4.z*b4.x; acc[2][1] += a4.z*b4.y; acc[2][2] += a4.z*b4.z; acc[2][3] += a4.z*b4.w;
      acc[3][0] += a4.w*b4.x; acc[3][1] += a4.w*b4.y; acc[3][2] += a4.w*b4.z; acc[3][3] += a4.w*b4.w;
    }
    __syncthreads();
  }

#pragma unroll
  for (int r = 0; r < 4; ++r)
#pragma unroll
    for (int c = 0; c < 4; ++c)
      unsafeAtomicAdd(&out_acc[(m0 + 4*ty + r) * 256 + n0 + 4*tx + c], acc[r][c]);
}

// ---------------- finalize: out = acc + b2 + xaug; loss partials ----------------
__global__ __launch_bounds__(256) void finalize_kernel(const float* __restrict__ out_acc,
                                                       const float* __restrict__ b2,
                                                       const float* __restrict__ xaug,
                                                       const float* __restrict__ yref,
                                                       float* __restrict__ d_out,
                                                       double* __restrict__ loss_acc,
                                                       unsigned int* __restrict__ cnt_acc)
{
  __shared__ double sred[4];
  __shared__ unsigned int cred[4];
  int i = blockIdx.x * 256 + threadIdx.x;
  int n = i & 255;
  float v = out_acc[i] + b2[n] + xaug[i];
  d_out[1 + i] = v;
  float yv = yref[i];
  bool valid = (yv != 0.0f);
  float df = v - yv;
  double lsd = valid ? (double)df * (double)df : 0.0;
#pragma unroll
  for (int off = 32; off > 0; off >>= 1) lsd += __shfl_down(lsd, off, 64);
  unsigned long long bal = __ballot(valid);
  int wvx = threadIdx.x >> 6, ln = threadIdx.x & 63;
  if (ln == 0) { sred[wvx] = lsd; cred[wvx] = (unsigned int)__popcll(bal); }
  __syncthreads();
  if (threadIdx.x == 0) {
    double s = sred[0] + sred[1] + sred[2] + sred[3];
    unsigned int c = cred[0] + cred[1] + cred[2] + cred[3];
    atomicAdd(loss_acc, s);
    atomicAdd(cnt_acc, c);
  }
}

__global__ void loss_kernel(const double* __restrict__ loss_acc,
                            const unsigned int* __restrict__ cnt_acc,
                            float* __restrict__ d_out)
{
  d_out[0] = (float)(loss_acc[0] / (double)cnt_acc[0]);
}

// ---------------- launch ----------------
extern "C" void kernel_launch(void* const* d_in, const int* in_sizes, int n_in,
                              void* d_out, int out_size, void* d_ws, size_t ws_size,
                              hipStream_t stream) {
  const float* x    = (const float*)d_in[0];
  const float* y    = (const float*)d_in[1];
  const float* W1   = (const float*)d_in[2];
  const float* b1   = (const float*)d_in[3];
  const float* W2   = (const float*)d_in[4];
  const float* b2   = (const float*)d_in[5];
  const float* freq = (const float*)d_in[6];
  float* out = (float*)d_out;

  char* ws = (char*)d_ws;
  float*  xaug = (float*)(ws);                        // 1 MB
  float*  h    = (float*)(ws + (1u<<20));             // 4 MB
  float*  mkf  = (float*)(ws + 5u*(1u<<20));          // 4 MB
  float*  oacc = (float*)(ws + 9u*(1u<<20));          // 1 MB
  double* lacc = (double*)(ws + 10u*(1u<<20));        // 8 B
  unsigned int* cacc = (unsigned int*)(ws + 10u*(1u<<20) + 8u);

  hipMemsetAsync(ws + 9u*(1u<<20), 0, (1u<<20) + 16u, stream);

  mask_kernel  <<<4096, 256, 0, stream>>>(freq, mkf);
  argaug_kernel<<<1024, 256, 0, stream>>>(x, y, xaug);
  gemm1_kernel <<<dim3(16,16),  256, 0, stream>>>(xaug, W1, b1, mkf, h);
  gemm2_kernel <<<dim3(16,4,4), 256, 0, stream>>>(h, W2, oacc);
  finalize_kernel<<<1024, 256, 0, stream>>>(oacc, b2, xaug, y, out, lacc, cacc);
  loss_kernel  <<<1, 1, 0, stream>>>(lacc, cacc, out);
}

// Round 11
// 240.178 us; speedup vs baseline: 1.3260x; 1.0429x over previous
//
#include <hip/hip_runtime.h>
#include <stdint.h>

#define IDIM 256

// ---------------- threefry2x32 (key = [0,42]), JAX partitionable draw ----------------
__device__ __forceinline__ uint32_t rotl32(uint32_t x, int r){ return (x<<r)|(x>>(32-r)); }

__device__ __forceinline__ uint32_t threefry_xor(uint32_t x0, uint32_t x1){
  const uint32_t k0 = 0u, k1 = 42u;
  const uint32_t k2 = 0x1BD11BDAu ^ k0 ^ k1;
  x0 += k0; x1 += k1;
#define TFR(r) { x0 += x1; x1 = rotl32(x1, r); x1 ^= x0; }
  TFR(13) TFR(15) TFR(26) TFR(6)  x0 += k1; x1 += k2 + 1u;
  TFR(17) TFR(29) TFR(16) TFR(24) x0 += k2; x1 += k0 + 2u;
  TFR(13) TFR(15) TFR(26) TFR(6)  x0 += k0; x1 += k1 + 3u;
  TFR(17) TFR(29) TFR(16) TFR(24) x0 += k1; x1 += k2 + 4u;
  TFR(13) TFR(15) TFR(26) TFR(6)  x0 += k2; x1 += k0 + 5u;
#undef TFR
  return x0 ^ x1;   // partitionable 32-bit combine [verified R7]
}

// ---------------- argaug: one-barrier all-theta sweep + wave-parallel fp64 rescue ----
// R10 lesson: 2 barriers/theta force per-theta max_wave(work) = 2206 q-units.
// Build all 9 padded keys once (one barrier), rotate block assignment per theta
// (b=(wave+t)&3) -> per-wave totals ~1340 q-units. Inner FMA pattern identical to
// the R10-passing kernel (bit-identical sims; extra trailing pad terms are exact
// zeros). Rescue/selection semantics unchanged.
__global__ __launch_bounds__(256) void argaug_kernel(const float* __restrict__ x,
                                                     const float* __restrict__ y,
                                                     float* __restrict__ xaug)
{
  __shared__ float  xs[IDIM];
  __shared__ float  ys[IDIM];
  __shared__ float  ks[4672];      // 9 regions, region t: off[t], len 263+OL (255 left pad, 8 right)
  __shared__ double rv[256];
  __shared__ int    rk[256];
  __shared__ double cand_v[128];
  __shared__ int    cand_k[128];
  __shared__ int    list[128];
  __shared__ int    cnt;

  const int tid  = threadIdx.x;
  const int wave = tid >> 6;
  const int lane = tid & 63;
  const int row  = blockIdx.x;
  const int OFF[9] = {0, 391, 814, 1269, 1756, 2275, 2826, 3409, 4024};

  xs[tid] = x[row * IDIM + tid];
  ys[tid] = y[row * IDIM + tid];
  if (tid == 0) cnt = 0;
  __syncthreads();

  // build all padded resampled keys (fp64 index = numpy-exact)
#pragma unroll
  for (int t = 0; t < 9; ++t) {
    const int OL = 128 + 32 * t;
    const double ratio = 256.0 / (double)OL;
    const int base = OFF[t];
    for (int p = tid; p < 263 + OL; p += 256) {
      float v = 0.0f;
      int j = p - 255;
      if (j >= 0 && j < OL) v = xs[(int)floor((double)j * ratio)];
      ks[base + p] = v;
    }
  }
  __syncthreads();   // the only barrier before the argmax phase

  float sA[9], sB[9], sC[9];   // statically indexed via full unroll

#pragma unroll
  for (int t = 0; t < 9; ++t) {
    const int OL  = 128 + 32 * t;
    const int nsh = OL + 255;
    const int b   = (wave + t) & 3;          // rotated block assignment (load balance)
    const int sb  = 192 * b + 3 * lane;
    const int qlo = (b == 0) ? 64 : 0;       // skipped terms are exact zeros
    const int qhi = min(256, nsh - sb);      // per-lane; trailing reads land in pad zeros
    const int base = OFF[t] + sb;            // ks index for q is base + q

    float a0=0.f,a1=0.f,a2=0.f, n0=0.f,n1=0.f,n2=0.f;
    if (qhi > qlo) {
      int p = base + qlo;
      float c0 = ks[p], c1 = ks[p+1], c2 = ks[p+2], c3;
      for (int q = qlo; q < qhi; q += 4) {
        float4 y4 = *(const float4*)&ys[q];
        a0 += y4.x*c0; n0 += c0*c0;
        a1 += y4.x*c1; n1 += c1*c1;
        a2 += y4.x*c2; n2 += c2*c2;
        c3 = ks[p+3];
        a0 += y4.y*c1; a1 += y4.y*c2; a2 += y4.y*c3; n0 += c1*c1; n1 += c2*c2; n2 += c3*c3;
        c0 = ks[p+4];
        a0 += y4.z*c2; a1 += y4.z*c3; a2 += y4.z*c0; n0 += c2*c2; n1 += c3*c3; n2 += c0*c0;
        c1 = ks[p+5];
        a0 += y4.w*c3; a1 += y4.w*c0; a2 += y4.w*c1; n0 += c3*c3; n1 += c0*c0; n2 += c1*c1;
        c2 = ks[p+6];
        p += 4;
      }
    }
    sA[t] = (sb     < nsh && n0 > 0.f) ? a0 * __frsqrt_rn(n0) : -1.0e30f;
    sB[t] = (sb + 1 < nsh && n1 > 0.f) ? a1 * __frsqrt_rn(n1) : -1.0e30f;
    sC[t] = (sb + 2 < nsh && n2 > 0.f) ? a2 * __frsqrt_rn(n2) : -1.0e30f;
  }

  // fp32 maxima: global and theta0
  {
    float gm = -1.0e30f;
#pragma unroll
    for (int t = 0; t < 9; ++t) gm = fmaxf(gm, fmaxf(sA[t], fmaxf(sB[t], sC[t])));
    rv[tid] = (double)gm;
  }
  __syncthreads();
  for (int off = 128; off > 0; off >>= 1) {
    if (tid < off) rv[tid] = fmax(rv[tid], rv[tid+off]);
    __syncthreads();
  }
  const float gmax32 = (float)rv[0];
  __syncthreads();
  rv[tid] = (double)fmaxf(sA[0], fmaxf(sB[0], sC[0]));
  __syncthreads();
  for (int off = 128; off > 0; off >>= 1) {
    if (tid < off) rv[tid] = fmax(rv[tid], rv[tid+off]);
    __syncthreads();
  }
  const float t0max32 = (float)rv[0];

  // collect rescue candidates (eps = 1e-3 >> ~6e-5 fp32-vs-fp64 sim error bound)
  const float gthr = gmax32  - 1.0e-3f;
  const float tthr = t0max32 - 1.0e-3f;
#pragma unroll
  for (int t = 0; t < 9; ++t) {
    const int b  = (wave + t) & 3;
    const int sb = 192 * b + 3 * lane;
#pragma unroll
    for (int r = 0; r < 3; ++r) {
      float v = (r == 0) ? sA[t] : (r == 1) ? sB[t] : sC[t];
      if (v >= gthr || (t == 0 && v >= tthr)) {
        int id = atomicAdd(&cnt, 1);
        if (id < 128) list[id] = (t << 10) | (sb + r);
      }
    }
  }
  __syncthreads();
  const int m = min(cnt, 128);

  // fp64 exact recompute: one wave per candidate, butterfly reduce (deterministic;
  // identical window content => bitwise-identical value => lex-min (t,s) tie-break
  // reproduces the reference's first-occurrence semantics)
  for (int c = wave; c < m; c += 4) {
    const int slot = list[c];
    const int tt = slot >> 10, ss = slot & 1023;
    const int OLr = 128 + 32 * tt;
    const double ratior = 256.0 / (double)OLr;
    double a64 = 0.0, n64 = 0.0;
#pragma unroll
    for (int k = 0; k < 4; ++k) {
      int q = 4 * lane + k;
      int j = ss + q - 255;
      if (j >= 0 && j < OLr) {
        double cc = (double)xs[(int)floor((double)j * ratior)];
        a64 += (double)ys[q] * cc;
        n64 += cc * cc;
      }
    }
#pragma unroll
    for (int d = 1; d < 64; d <<= 1) {
      a64 += __shfl_xor(a64, d, 64);
      n64 += __shfl_xor(n64, d, 64);
    }
    if (lane == 0) {
      cand_v[c] = (n64 > 0.0) ? a64 / sqrt(n64) : -1.0e300;
      cand_k[c] = slot;
    }
  }
  __syncthreads();

  // reduce #1: global best among rescued, lex-first (t,s)
  rv[tid] = (tid < m) ? cand_v[tid] : -1.0e300;
  rk[tid] = (tid < m) ? cand_k[tid] : 0x3FFFFFFF;
  __syncthreads();
  for (int off = 128; off > 0; off >>= 1) {
    if (tid < off) {
      double v2 = rv[tid+off]; int k2 = rk[tid+off];
      if (v2 > rv[tid] || (v2 == rv[tid] && k2 < rk[tid])) { rv[tid] = v2; rk[tid] = k2; }
    }
    __syncthreads();
  }
  const double gbest = rv[0];
  const int    gk    = rk[0];
  __syncthreads();

  // reduce #2: theta0 best (fallback when gbest <= 0)
  rv[tid] = (tid < m && (cand_k[tid] >> 10) == 0) ? cand_v[tid] : -1.0e300;
  rk[tid] = (tid < m) ? cand_k[tid] : 0x3FFFFFFF;
  __syncthreads();
  for (int off = 128; off > 0; off >>= 1) {
    if (tid < off) {
      double v2 = rv[tid+off]; int k2 = rk[tid+off];
      if (v2 > rv[tid] || (v2 == rv[tid] && k2 < rk[tid])) { rv[tid] = v2; rk[tid] = k2; }
    }
    __syncthreads();
  }
  const int wk = (gbest > 0.0) ? gk : rk[0];

  const int tb = wk >> 10, sb2 = wk & 1023;
  const int OLb = 128 + 32 * tb;
  const double ratiob = 256.0 / (double)OLb;
  int j = sb2 + tid - 255;
  float v = 0.0f;
  if (j >= 0 && j < OLb) v = xs[(int)floor((double)j * ratiob)];
  xaug[row * IDIM + tid] = v;
}

// ---------------- GEMM1: h = (xaug @ W1 + b1) * mk (mask inline) + zero-init -------
__global__ __launch_bounds__(256) void gemm1_kernel(const float* __restrict__ A,
                                                    const float* __restrict__ W1,
                                                    const float* __restrict__ b1,
                                                    const float* __restrict__ freq,
                                                    float* __restrict__ h,
                                                    float* __restrict__ oacc,
                                                    double* __restrict__ lacc,
                                                    unsigned int* __restrict__ cacc,
                                                    unsigned int* __restrict__ done)
{
  // zero split-K accumulator + loss scalars; completes before gemm2/finalize (stream order)
  {
    const int gz = (blockIdx.y * 16 + blockIdx.x) * 256 + threadIdx.x;   // [0, 65536)
    float4 z; z.x = z.y = z.z = z.w = 0.f;
    *(float4*)&oacc[gz * 4] = z;                                          // covers 262144 floats
    if (gz == 0) { *lacc = 0.0; *cacc = 0u; *done = 0u; }
  }

  __shared__ float As[32][68];
  __shared__ float Bs[32][68];
  const int tid = threadIdx.x;
  const int m0 = blockIdx.x * 64;
  const int n0 = blockIdx.y * 64;
  const int tx = tid & 15, ty = tid >> 4;
  float acc[4][4] = {};

  for (int kt = 0; kt < 256; kt += 32) {
#pragma unroll
    for (int jj = 0; jj < 8; ++jj) {
      int f = tid + 256*jj;
      As[f & 31][f >> 5] = A[(m0 + (f >> 5)) * 256 + kt + (f & 31)];
    }
#pragma unroll
    for (int jj = 0; jj < 8; ++jj) {
      int f = tid + 256*jj;
      Bs[f >> 6][f & 63] = W1[(kt + (f >> 6)) * 1024 + n0 + (f & 63)];
    }
    __syncthreads();
#pragma unroll
    for (int kk = 0; kk < 32; ++kk) {
      float4 a4 = *(const float4*)&As[kk][4*ty];
      float4 b4 = *(const float4*)&Bs[kk][4*tx];
      acc[0][0] += a4.x*b4.x; acc[0][1] += a4.x*b4.y; acc[0][2] += a4.x*b4.z; acc[0][3] += a4.x*b4.w;
      acc[1][0] += a4.y*b4.x; acc[1][1] += a4.y*b4.y; acc[1][2] += a4.y*b4.z; acc[1][3] += a4.y*b4.w;
      acc[2][0] += a4.z*b4.x; acc[2][1] += a4.z*b4.y; acc[2][2] += a4.z*b4.z; acc[2][3] += a4.z*b4.w;
      acc[3][0] += a4.w*b4.x; acc[3][1] += a4.w*b4.y; acc[3][2] += a4.w*b4.z; acc[3][3] += a4.w*b4.w;
    }
    __syncthreads();
  }

  float4 bias = *(const float4*)&b1[n0 + 4*tx];
  float4 fq4  = *(const float4*)&freq[n0 + 4*tx];
#pragma unroll
  for (int r = 0; r < 4; ++r) {
    const int mm = m0 + 4*ty + r;
    const uint32_t ib = (uint32_t)(mm * 1024 + n0 + 4*tx);
    float4 o;
    {
      float u = __uint_as_float((threefry_xor(0u, ib+0u) >> 9) | 0x3F800000u) - 1.0f;
      o.x = (acc[r][0] + bias.x) * ((u < fq4.x) ? 1.0f : 0.0f);
      u = __uint_as_float((threefry_xor(0u, ib+1u) >> 9) | 0x3F800000u) - 1.0f;
      o.y = (acc[r][1] + bias.y) * ((u < fq4.y) ? 1.0f : 0.0f);
      u = __uint_as_float((threefry_xor(0u, ib+2u) >> 9) | 0x3F800000u) - 1.0f;
      o.z = (acc[r][2] + bias.z) * ((u < fq4.z) ? 1.0f : 0.0f);
      u = __uint_as_float((threefry_xor(0u, ib+3u) >> 9) | 0x3F800000u) - 1.0f;
      o.w = (acc[r][3] + bias.w) * ((u < fq4.w) ? 1.0f : 0.0f);
    }
    *(float4*)&h[mm * 1024 + n0 + 4*tx] = o;
  }
}

// ---------------- GEMM2 (split-K=4): out_acc += h @ W2 --------------------------------
__global__ __launch_bounds__(256) void gemm2_kernel(const float* __restrict__ h,
                                                    const float* __restrict__ W2,
                                                    float* __restrict__ out_acc)
{
  __shared__ float As[32][68];
  __shared__ float Bs[32][68];
  const int tid = threadIdx.x;
  const int m0 = blockIdx.x * 64;
  const int n0 = blockIdx.y * 64;
  const int kz = blockIdx.z * 256;
  const int tx = tid & 15, ty = tid >> 4;
  float acc[4][4] = {};

  for (int kt = 0; kt < 256; kt += 32) {
#pragma unroll
    for (int jj = 0; jj < 8; ++jj) {
      int f = tid + 256*jj;
      As[f & 31][f >> 5] = h[(m0 + (f >> 5)) * 1024 + kz + kt + (f & 31)];
    }
#pragma unroll
    for (int jj = 0; jj < 8; ++jj) {
      int f = tid + 256*jj;
      Bs[f >> 6][f & 63] = W2[(kz + kt + (f >> 6)) * 256 + n0 + (f & 63)];
    }
    __syncthreads();
#pragma unroll
    for (int kk = 0; kk < 32; ++kk) {
      float4 a4 = *(const float4*)&As[kk][4*ty];
      float4 b4 = *(const float4*)&Bs[kk][4*tx];
      acc[0][0] += a4.x*b4.x; acc[0][1] += a4.x*b4.y; acc[0][2] += a4.x*b4.z; acc[0][3] += a4.x*b4.w;
      acc[1][0] += a4.y*b4.x; acc[1][1] += a4.y*b4.y; acc[1][2] += a4.y*b4.z; acc[1][3] += a4.y*b4.w;
      acc[2][0] += a4.z*b4.x; acc[2][1] += a4.z*b4.y; acc[2][2] += a4.z*b4.z; acc[2][3] += a4.z*b4.w;
      acc[3][0] += a4.w*b4.x; acc[3][1] += a4.w*b4.y; acc[3][2] += a4.w*b4.z; acc[3][3] += a4.w*b4.w;
    }
    __syncthreads();
  }

#pragma unroll
  for (int r = 0; r < 4; ++r)
#pragma unroll
    for (int c = 0; c < 4; ++c)
      unsafeAtomicAdd(&out_acc[(m0 + 4*ty + r) * 256 + n0 + 4*tx + c], acc[r][c]);
}

// ---------------- finalize: out = acc + b2 + xaug; loss via last-block ----------------
__global__ __launch_bounds__(256) void finalize_kernel(const float* __restrict__ out_acc,
                                                       const float* __restrict__ b2,
                                                       const float* __restrict__ xaug,
                                                       const float* __restrict__ yref,
                                                       float* __restrict__ d_out,
                                                       double* __restrict__ lacc,
                                                       unsigned int* __restrict__ cacc,
                                                       unsigned int* __restrict__ done)
{
  __shared__ double sred[4];
  __shared__ unsigned int cred[4];
  int i = blockIdx.x * 256 + threadIdx.x;
  int n = i & 255;
  float v = out_acc[i] + b2[n] + xaug[i];
  d_out[1 + i] = v;
  float yv = yref[i];
  bool valid = (yv != 0.0f);
  float df = v - yv;
  double lsd = valid ? (double)df * (double)df : 0.0;
#pragma unroll
  for (int off = 32; off > 0; off >>= 1) lsd += __shfl_down(lsd, off, 64);
  unsigned long long bal = __ballot(valid);
  int wvx = threadIdx.x >> 6, ln = threadIdx.x & 63;
  if (ln == 0) { sred[wvx] = lsd; cred[wvx] = (unsigned int)__popcll(bal); }
  __syncthreads();
  if (threadIdx.x == 0) {
    double s = sred[0] + sred[1] + sred[2] + sred[3];
    unsigned int c = cred[0] + cred[1] + cred[2] + cred[3];
    atomicAdd(lacc, s);
    atomicAdd(cacc, c);
    __threadfence();
    unsigned int old = atomicAdd(done, 1u);
    if (old == gridDim.x - 1u) {                 // last block: all adds visible
      double tot = atomicAdd(lacc, 0.0);         // coherent read via atomic RMW
      unsigned int cc = atomicAdd(cacc, 0u);
      d_out[0] = (float)(tot / (double)cc);
    }
  }
}

// ---------------- launch (4 dispatches) ----------------
extern "C" void kernel_launch(void* const* d_in, const int* in_sizes, int n_in,
                              void* d_out, int out_size, void* d_ws, size_t ws_size,
                              hipStream_t stream) {
  const float* x    = (const float*)d_in[0];
  const float* y    = (const float*)d_in[1];
  const float* W1   = (const float*)d_in[2];
  const float* b1   = (const float*)d_in[3];
  const float* W2   = (const float*)d_in[4];
  const float* b2   = (const float*)d_in[5];
  const float* freq = (const float*)d_in[6];
  float* out = (float*)d_out;

  char* ws = (char*)d_ws;
  float*  xaug = (float*)(ws);                        // 1 MB
  float*  h    = (float*)(ws + (1u<<20));             // 4 MB
  float*  oacc = (float*)(ws + 9u*(1u<<20));          // 1 MB (zeroed by gemm1)
  double* lacc = (double*)(ws + 10u*(1u<<20));        // 8 B
  unsigned int* cacc = (unsigned int*)(ws + 10u*(1u<<20) + 8u);
  unsigned int* done = (unsigned int*)(ws + 10u*(1u<<20) + 12u);

  argaug_kernel<<<1024, 256, 0, stream>>>(x, y, xaug);
  gemm1_kernel <<<dim3(16,16),  256, 0, stream>>>(xaug, W1, b1, freq, h, oacc, lacc, cacc, done);
  gemm2_kernel <<<dim3(16,4,4), 256, 0, stream>>>(h, W2, oacc);
  finalize_kernel<<<1024, 256, 0, stream>>>(oacc, b2, xaug, y, out, lacc, cacc, done);
}